// Round 7
// baseline (149.764 us; speedup 1.0000x reference)
//
#include <hip/hip_runtime.h>

// VectorQuantizer: x [2,8,48,48,48] f32, embed [512,8] f32
// d_out: loss (1) | out (1769472) | encodings (221184*512 = 113246208)
// R7: fused argmin + DEVICE-DENSE striped zero-stream (fill-kernel address
// pattern), ones scattered by a second kernel (stream order = zero<one).
// argmin geometry = R5 (864 blocks x 64 thr x 4 pts, LDS-amortized).

#pragma clang fp contract(off)

#define KCB   512
#define SPB   110592          // 48^3
#define NBLK  864             // 221184 / 256 rows per block
#define OUT_OFF 1
#define ENC_OFF 1769473LL     // 1 + 2*8*SPB ; %4 == 1
#define G4_BASE 442369LL      // (ENC_OFF + 3) / 4 : first aligned float4
#define G4_COUNT 28311551LL   // aligned float4 slots in enc region
#define TAIL_IDX 115015680LL  // ENC_OFF + 113246208 - 1
#define STRIPE 55296LL        // 864 blocks * 64 lanes float4 per sub-stripe

__global__ __launch_bounds__(64) void vq_main(const float* __restrict__ x,
                                              const float* __restrict__ e,
                                              float* __restrict__ dout,
                                              unsigned short* __restrict__ idxout,
                                              float* __restrict__ partials) {
    __shared__ float cb[KCB * 8];    // 16 KB codebook [512][8]
    __shared__ float sse[KCB];       // 2 KB row norms
    const int L   = threadIdx.x;     // 0..63, one wave per block
    const int blk = blockIdx.x;
    const int b   = (blk >= 432) ? 1 : 0;          // blocks don't straddle batch
    const int s0  = blk * 256 - b * SPB;           // row q*64+L -> spatial s0+q*64+L

    // x loads early: xv[q][c], coalesced 256B per (c,q)
    const float* xb = x + (size_t)b * (8 * SPB) + s0 + L;
    float xv[4][8];
    #pragma unroll
    for (int q = 0; q < 4; ++q)
        #pragma unroll
        for (int c = 0; c < 8; ++c)
            xv[q][c] = xb[(size_t)c * SPB + q * 64];

    // stage codebook (1024 float4, 16 per lane)
    {
        float4* cb4 = (float4*)cb;
        const float4* e4 = (const float4*)e;
        #pragma unroll
        for (int i = 0; i < 16; ++i) cb4[i * 64 + L] = e4[i * 64 + L];
    }
    __syncthreads();
    // row norms: numpy 8-elem pairwise tree (contract off: squares round first)
    #pragma unroll
    for (int j = 0; j < 8; ++j) {
        int r = j * 64 + L;
        const float* row = cb + (r << 3);
        sse[r] = ((row[0]*row[0] + row[1]*row[1]) + (row[2]*row[2] + row[3]*row[3]))
               + ((row[4]*row[4] + row[5]*row[5]) + (row[6]*row[6] + row[7]*row[7]));
    }
    __syncthreads();

    // sum(x^2), numpy tree, per point
    float sx[4];
    #pragma unroll
    for (int q = 0; q < 4; ++q)
        sx[q] = ((xv[q][0]*xv[q][0] + xv[q][1]*xv[q][1]) + (xv[q][2]*xv[q][2] + xv[q][3]*xv[q][3]))
              + ((xv[q][4]*xv[q][4] + xv[q][5]*xv[q][5]) + (xv[q][6]*xv[q][6] + xv[q][7]*xv[q][7]));

    float bestE[4], bestO[4];
    int   idxE[4], idxO[4];
    #pragma unroll
    for (int q = 0; q < 4; ++q) {
        bestE[q] = 3.402823466e38f; bestO[q] = 3.402823466e38f;
        idxE[q] = 0; idxO[q] = 1;
    }

    // dense striped zero-stream: sub-stripe m (m = 2i+sub) is the contiguous
    // device-wide span [m*STRIPE, (m+1)*STRIPE) of aligned float4 slots;
    // this wave owns the 1KB piece at blk*64+L within each sub-stripe.
    float4* g4 = (float4*)dout + G4_BASE;
    const long long my4 = (long long)blk * 64 + L;
    const float4 z4 = make_float4(0.f, 0.f, 0.f, 0.f);
    const bool notLast = (blk != 863) || (L != 63);

    #pragma unroll 1
    for (int i = 0; i < 256; ++i) {
        const int k = i * 2;
        const float4* ek = (const float4*)(cb + (k << 3));  // rows k,k+1 (64B broadcast)
        float4 r0a = ek[0], r0b = ek[1], r1a = ek[2], r1b = ek[3];
        float2 s01 = *(const float2*)(sse + k);

        g4[(long long)(2 * i) * STRIPE + my4] = z4;
        if (i != 255 || notLast)                   // last slot of last stripe: OOB
            g4[(long long)(2 * i + 1) * STRIPE + my4] = z4;

        #pragma unroll
        for (int q = 0; q < 4; ++q) {
            float d0 =       xv[q][0] * r0a.x;
            d0 = __builtin_fmaf(xv[q][1], r0a.y, d0);
            d0 = __builtin_fmaf(xv[q][2], r0a.z, d0);
            d0 = __builtin_fmaf(xv[q][3], r0a.w, d0);
            d0 = __builtin_fmaf(xv[q][4], r0b.x, d0);
            d0 = __builtin_fmaf(xv[q][5], r0b.y, d0);
            d0 = __builtin_fmaf(xv[q][6], r0b.z, d0);
            d0 = __builtin_fmaf(xv[q][7], r0b.w, d0);
            float dist0 = __builtin_fmaf(-2.0f, d0, sx[q] + s01.x);

            float d1 =       xv[q][0] * r1a.x;
            d1 = __builtin_fmaf(xv[q][1], r1a.y, d1);
            d1 = __builtin_fmaf(xv[q][2], r1a.z, d1);
            d1 = __builtin_fmaf(xv[q][3], r1a.w, d1);
            d1 = __builtin_fmaf(xv[q][4], r1b.x, d1);
            d1 = __builtin_fmaf(xv[q][5], r1b.y, d1);
            d1 = __builtin_fmaf(xv[q][6], r1b.z, d1);
            d1 = __builtin_fmaf(xv[q][7], r1b.w, d1);
            float dist1 = __builtin_fmaf(-2.0f, d1, sx[q] + s01.y);

            bool l0 = dist0 < bestE[q];
            bestE[q] = l0 ? dist0 : bestE[q];
            idxE[q]  = l0 ? k     : idxE[q];
            bool l1 = dist1 < bestO[q];
            bestO[q] = l1 ? dist1 : bestO[q];
            idxO[q]  = l1 ? k + 1 : idxO[q];
        }
    }

    // merge chains (global first-min tie rule) and record indices
    int bidx[4];
    #pragma unroll
    for (int q = 0; q < 4; ++q) {
        bool ow = (bestO[q] < bestE[q]) || ((bestO[q] == bestE[q]) && (idxO[q] < idxE[q]));
        bidx[q] = ow ? idxO[q] : idxE[q];
        idxout[blk * 256 + q * 64 + L] = (unsigned short)bidx[q];
    }

    // out region + loss partial
    float part = 0.0f;
    float* outp = dout + OUT_OFF + (size_t)b * (8 * SPB) + s0 + L;
    #pragma unroll
    for (int q = 0; q < 4; ++q) {
        const float4* qr4 = (const float4*)(cb + (bidx[q] << 3));
        float4 qa = qr4[0], qb = qr4[1];
        float qv[8] = {qa.x, qa.y, qa.z, qa.w, qb.x, qb.y, qb.z, qb.w};
        #pragma unroll
        for (int c = 0; c < 8; ++c) {
            float dq = qv[c] - xv[q][c];
            part += dq * dq;
            outp[(size_t)c * SPB + q * 64] = qv[c];
        }
    }

    // deterministic wave tree reduction
    #pragma unroll
    for (int off = 32; off > 0; off >>= 1)
        part += __shfl_down(part, off, 64);
    if (L == 0) partials[blk] = part;
}

// K2: scatter the ones (runs after ALL of K1's zero stores - stream order),
// plus the 4 unaligned edge floats of the enc region.
__global__ __launch_bounds__(256) void scatter_ones(const unsigned short* __restrict__ idx,
                                                    float* __restrict__ dout) {
    const int n = blockIdx.x * 256 + threadIdx.x;   // < 221184 (864*256)
    const int k = idx[n];
    if (n == 0) {
        // head floats (enc cols 0..2 of row 0) and tail float (col 511 of last row)
        dout[ENC_OFF]     = (k == 0) ? 1.0f : 0.0f;  // covered below too? no: head
        dout[ENC_OFF + 1] = (k == 1) ? 1.0f : 0.0f;
        dout[ENC_OFF + 2] = (k == 2) ? 1.0f : 0.0f;
    }
    if (n == 221183) {
        dout[TAIL_IDX] = (k == 511) ? 1.0f : 0.0f;
    }
    // the aligned-region one (skip if it lives in head/tail scalars)
    long long f = (long long)n * KCB + k;           // float index within enc
    if (f >= 3 && f < 113246207LL)
        dout[ENC_OFF + f] = 1.0f;
    else if (n == 0)                                 // k<3 handled above
        ;
}

__global__ __launch_bounds__(256) void loss_kernel(const float* __restrict__ partials,
                                                   float* __restrict__ dout) {
    __shared__ float sred[256];
    int t = threadIdx.x;
    float a = 0.0f;
    for (int j = t; j < NBLK; j += 256) a += partials[j];  // fixed order
    sred[t] = a;
    __syncthreads();
    for (int off = 128; off > 0; off >>= 1) {
        if (t < off) sred[t] += sred[t + off];
        __syncthreads();
    }
    if (t == 0) {
        float m = sred[0] / 1769472.0f;
        m = fminf(fmaxf(m, 0.0f), 10.0f);
        dout[0] = m + 0.25f * m;   // q_latent + beta*e_latent (equal values)
    }
}

extern "C" void kernel_launch(void* const* d_in, const int* in_sizes, int n_in,
                              void* d_out, int out_size, void* d_ws, size_t ws_size,
                              hipStream_t stream) {
    const float* x = (const float*)d_in[0];
    const float* e = (const float*)d_in[1];
    float* dout = (float*)d_out;
    unsigned short* idx = (unsigned short*)d_ws;            // 221184 u16 = 432 KB
    float* partials     = (float*)((char*)d_ws + 221184 * sizeof(unsigned short));

    hipLaunchKernelGGL(vq_main,      dim3(NBLK), dim3(64),  0, stream, x, e, dout, idx, partials);
    hipLaunchKernelGGL(scatter_ones, dim3(NBLK), dim3(256), 0, stream, idx, dout);
    hipLaunchKernelGGL(loss_kernel,  dim3(1),    dim3(256), 0, stream, partials, dout);
}

// Round 8
// 132.206 us; speedup vs baseline: 1.1328x; 1.1328x over previous
//
#include <hip/hip_runtime.h>

// VectorQuantizer: x [2,8,48,48,48] f32, embed [512,8] f32
// d_out: loss (1) | out (1769472) | encodings (221184*512 = 113246208)
// R8: ONE kernel, role-split blocks:
//   blocks 0..215    : argmin (256 thr = 4 waves, 4 pts/thread, LDS codebook)
//   blocks 216..2263 : dense grid-stride zero-fill of the enc region
//                      (the exact pattern measured at ~6.7 TB/s on this chip)
// Fill saturates HBM writes while argmin computes on idle VALU/LDS pipes.
// K2 scatters the 221184 ones (stream order => after all zeros) + loss.

#pragma clang fp contract(off)

#define KCB   512
#define SPB   110592          // 48^3
#define NPTS  221184
#define ABLK  216             // argmin blocks (1024 points each)
#define FBLK  2048            // fill blocks
#define OUT_OFF 1
#define ENC_OFF 1769473LL     // 1 + 2*8*SPB ; %4 == 1
#define G4_BASE 442369LL      // (ENC_OFF + 3) / 4 : first aligned float4
#define G4_COUNT 28311551LL   // aligned float4 slots in enc region
#define TAIL_IDX 115015680LL  // ENC_OFF + 113246208 - 1

__global__ __launch_bounds__(256) void vq_fused(const float* __restrict__ x,
                                                const float* __restrict__ e,
                                                float* __restrict__ dout,
                                                unsigned short* __restrict__ idxout,
                                                float* __restrict__ partials) {
    __shared__ float cb[KCB * 8];    // 16 KB codebook [512][8]
    __shared__ float sse[KCB];       // 2 KB row norms
    __shared__ float sred[256];
    const int t = threadIdx.x;

    if (blockIdx.x >= ABLK) {
        // ---------------- fill role: dense grid-stride zero sweep ----------------
        const int f = blockIdx.x - ABLK;                 // 0..2047
        const long long g = (long long)f * 256 + t;      // 0..524287
        float4* g4 = (float4*)dout + G4_BASE;
        const float4 z4 = make_float4(0.f, 0.f, 0.f, 0.f);
        #pragma unroll 1
        for (long long j = g; j < G4_COUNT; j += (long long)FBLK * 256)
            g4[j] = z4;
        return;
    }

    // ---------------- argmin role ----------------
    const int w   = t >> 6;          // wave 0..3
    const int L   = t & 63;          // lane
    const int blk = blockIdx.x;      // 0..215, block owns points [blk*1024, +1024)
    const int b   = (blk >= 108) ? 1 : 0;            // 1024 | SPB -> no straddle
    const int s0  = blk * 1024 - b * SPB + w * 256;  // wave's 256-point chunk

    // x loads early: xv[q][c], coalesced per (c,q)
    const float* xb = x + (size_t)b * (8 * SPB) + s0 + L;
    float xv[4][8];
    #pragma unroll
    for (int q = 0; q < 4; ++q)
        #pragma unroll
        for (int c = 0; c < 8; ++c)
            xv[q][c] = xb[(size_t)c * SPB + q * 64];

    // stage codebook (1024 float4)
    {
        float4* cb4 = (float4*)cb;
        const float4* e4 = (const float4*)e;
        #pragma unroll
        for (int i = 0; i < 4; ++i) cb4[i * 256 + t] = e4[i * 256 + t];
    }
    __syncthreads();
    // row norms: numpy 8-elem pairwise tree (contract off: squares round first)
    #pragma unroll
    for (int j = 0; j < 2; ++j) {
        int r = j * 256 + t;
        const float* row = cb + (r << 3);
        sse[r] = ((row[0]*row[0] + row[1]*row[1]) + (row[2]*row[2] + row[3]*row[3]))
               + ((row[4]*row[4] + row[5]*row[5]) + (row[6]*row[6] + row[7]*row[7]));
    }
    __syncthreads();

    // sum(x^2), numpy tree, per point
    float sx[4];
    #pragma unroll
    for (int q = 0; q < 4; ++q)
        sx[q] = ((xv[q][0]*xv[q][0] + xv[q][1]*xv[q][1]) + (xv[q][2]*xv[q][2] + xv[q][3]*xv[q][3]))
              + ((xv[q][4]*xv[q][4] + xv[q][5]*xv[q][5]) + (xv[q][6]*xv[q][6] + xv[q][7]*xv[q][7]));

    float bestE[4], bestO[4];
    int   idxE[4], idxO[4];
    #pragma unroll
    for (int q = 0; q < 4; ++q) {
        bestE[q] = 3.402823466e38f; bestO[q] = 3.402823466e38f;
        idxE[q] = 0; idxO[q] = 1;
    }

    // argmin_k fl( fl(sx+se_k) - 2*dot_k ), first-min tie rule; dual chains.
    #pragma unroll 1
    for (int i = 0; i < 256; ++i) {
        const int k = i * 2;
        const float4* ek = (const float4*)(cb + (k << 3));  // rows k,k+1 (broadcast)
        float4 r0a = ek[0], r0b = ek[1], r1a = ek[2], r1b = ek[3];
        float2 s01 = *(const float2*)(sse + k);

        #pragma unroll
        for (int q = 0; q < 4; ++q) {
            float d0 =       xv[q][0] * r0a.x;
            d0 = __builtin_fmaf(xv[q][1], r0a.y, d0);
            d0 = __builtin_fmaf(xv[q][2], r0a.z, d0);
            d0 = __builtin_fmaf(xv[q][3], r0a.w, d0);
            d0 = __builtin_fmaf(xv[q][4], r0b.x, d0);
            d0 = __builtin_fmaf(xv[q][5], r0b.y, d0);
            d0 = __builtin_fmaf(xv[q][6], r0b.z, d0);
            d0 = __builtin_fmaf(xv[q][7], r0b.w, d0);
            float dist0 = __builtin_fmaf(-2.0f, d0, sx[q] + s01.x);

            float d1 =       xv[q][0] * r1a.x;
            d1 = __builtin_fmaf(xv[q][1], r1a.y, d1);
            d1 = __builtin_fmaf(xv[q][2], r1a.z, d1);
            d1 = __builtin_fmaf(xv[q][3], r1a.w, d1);
            d1 = __builtin_fmaf(xv[q][4], r1b.x, d1);
            d1 = __builtin_fmaf(xv[q][5], r1b.y, d1);
            d1 = __builtin_fmaf(xv[q][6], r1b.z, d1);
            d1 = __builtin_fmaf(xv[q][7], r1b.w, d1);
            float dist1 = __builtin_fmaf(-2.0f, d1, sx[q] + s01.y);

            bool l0 = dist0 < bestE[q];
            bestE[q] = l0 ? dist0 : bestE[q];
            idxE[q]  = l0 ? k     : idxE[q];
            bool l1 = dist1 < bestO[q];
            bestO[q] = l1 ? dist1 : bestO[q];
            idxO[q]  = l1 ? k + 1 : idxO[q];
        }
    }

    // merge chains (global first-min tie rule), record indices
    int bidx[4];
    #pragma unroll
    for (int q = 0; q < 4; ++q) {
        bool ow = (bestO[q] < bestE[q]) || ((bestO[q] == bestE[q]) && (idxO[q] < idxE[q]));
        bidx[q] = ow ? idxO[q] : idxE[q];
        idxout[blk * 1024 + w * 256 + q * 64 + L] = (unsigned short)bidx[q];
    }

    // out region + loss partial
    float part = 0.0f;
    float* outp = dout + OUT_OFF + (size_t)b * (8 * SPB) + s0 + L;
    #pragma unroll
    for (int q = 0; q < 4; ++q) {
        const float4* qr4 = (const float4*)(cb + (bidx[q] << 3));
        float4 qa = qr4[0], qb = qr4[1];
        float qv[8] = {qa.x, qa.y, qa.z, qa.w, qb.x, qb.y, qb.z, qb.w};
        #pragma unroll
        for (int c = 0; c < 8; ++c) {
            float dq = qv[c] - xv[q][c];
            part += dq * dq;
            outp[(size_t)c * SPB + q * 64] = qv[c];
        }
    }

    // deterministic block reduction (256 -> 1)
    sred[t] = part;
    __syncthreads();
    for (int off = 128; off > 0; off >>= 1) {
        if (t < off) sred[t] += sred[t + off];
        __syncthreads();
    }
    if (t == 0) partials[blk] = sred[0];
}

// K2: scatter the ones (after ALL K1 zero stores - stream order), write the
// 4 unaligned edge floats, and (block 0) the loss.
__global__ __launch_bounds__(256) void scatter_ones(const unsigned short* __restrict__ idx,
                                                    const float* __restrict__ partials,
                                                    float* __restrict__ dout) {
    const int t = threadIdx.x;
    const int n = blockIdx.x * 256 + t;             // < 221184 (864 blocks)
    const int k = idx[n];
    if (n == 0) {
        dout[ENC_OFF]     = (k == 0) ? 1.0f : 0.0f;
        dout[ENC_OFF + 1] = (k == 1) ? 1.0f : 0.0f;
        dout[ENC_OFF + 2] = (k == 2) ? 1.0f : 0.0f;
    }
    if (n == NPTS - 1) {
        dout[TAIL_IDX] = (k == 511) ? 1.0f : 0.0f;
    }
    long long f = (long long)n * KCB + k;           // float index within enc
    if (f >= 3 && f < 113246207LL)
        dout[ENC_OFF + f] = 1.0f;

    if (blockIdx.x == 0) {
        __shared__ float sl[256];
        float a = (t < ABLK) ? partials[t] : 0.0f;  // fixed order, deterministic
        sl[t] = a;
        __syncthreads();
        for (int off = 128; off > 0; off >>= 1) {
            if (t < off) sl[t] += sl[t + off];
            __syncthreads();
        }
        if (t == 0) {
            float m = sl[0] / 1769472.0f;
            m = fminf(fmaxf(m, 0.0f), 10.0f);
            dout[0] = m + 0.25f * m;   // q_latent + beta*e_latent (equal values)
        }
    }
}

extern "C" void kernel_launch(void* const* d_in, const int* in_sizes, int n_in,
                              void* d_out, int out_size, void* d_ws, size_t ws_size,
                              hipStream_t stream) {
    const float* x = (const float*)d_in[0];
    const float* e = (const float*)d_in[1];
    float* dout = (float*)d_out;
    unsigned short* idx = (unsigned short*)d_ws;            // 221184 u16 = 432 KB
    float* partials     = (float*)((char*)d_ws + NPTS * sizeof(unsigned short));

    hipLaunchKernelGGL(vq_fused,     dim3(ABLK + FBLK), dim3(256), 0, stream,
                       x, e, dout, idx, partials);
    hipLaunchKernelGGL(scatter_ones, dim3(NPTS / 256),  dim3(256), 0, stream,
                       idx, partials, dout);
}

// Round 9
// 126.119 us; speedup vs baseline: 1.1875x; 1.0483x over previous
//
#include <hip/hip_runtime.h>

// VectorQuantizer: x [2,8,48,48,48] f32, embed [512,8] f32
// d_out: loss (1) | out (1769472) | encodings (221184*512 = 113246208)
// R9 = R5 (best known, 121 us) + per-block PHASE ROTATION of the fused
// zero-store schedule: iter i writes slot-pair (i + 149*blk) mod 256, so the
// 864 concurrent write fronts are uniformly spread mod 512KB at every
// instant -> full HBM channel coverage even in lockstep.

#pragma clang fp contract(off)

#define KCB   512
#define SPB   110592          // 48^3
#define NBLK  864             // 221184 / 256 rows per block
#define OUT_OFF 1
#define ENC_OFF 1769473LL     // 1 + 2*8*SPB ; %4 == 1
#define G4_BASE 442369LL      // (ENC_OFF + 3) / 4

__global__ __launch_bounds__(64) void vq_main(const float* __restrict__ x,
                                              const float* __restrict__ e,
                                              float* __restrict__ dout,
                                              float* __restrict__ partials) {
    __shared__ float cb[KCB * 8];    // 16 KB codebook [512][8]
    __shared__ float sse[KCB];       // 2 KB row norms
    const int L   = threadIdx.x;     // 0..63, one wave per block
    const int blk = blockIdx.x;
    const int b   = (blk >= 432) ? 1 : 0;          // blocks don't straddle batch
    const int s0  = blk * 256 - b * SPB;           // row q*64+L -> spatial s0+q*64+L

    // x loads early: xv[q][c], coalesced 256B per (c,q)
    const float* xb = x + (size_t)b * (8 * SPB) + s0 + L;
    float xv[4][8];
    #pragma unroll
    for (int q = 0; q < 4; ++q)
        #pragma unroll
        for (int c = 0; c < 8; ++c)
            xv[q][c] = xb[(size_t)c * SPB + q * 64];

    // stage codebook (1024 float4, 16 per lane)
    {
        float4* cb4 = (float4*)cb;
        const float4* e4 = (const float4*)e;
        #pragma unroll
        for (int i = 0; i < 16; ++i) cb4[i * 64 + L] = e4[i * 64 + L];
    }
    __syncthreads();
    // row norms: numpy 8-elem pairwise tree (contract off: squares round first)
    #pragma unroll
    for (int j = 0; j < 8; ++j) {
        int r = j * 64 + L;
        const float* row = cb + (r << 3);
        sse[r] = ((row[0]*row[0] + row[1]*row[1]) + (row[2]*row[2] + row[3]*row[3]))
               + ((row[4]*row[4] + row[5]*row[5]) + (row[6]*row[6] + row[7]*row[7]));
    }
    __syncthreads();

    // sum(x^2), numpy tree, per point
    float sx[4];
    #pragma unroll
    for (int q = 0; q < 4; ++q)
        sx[q] = ((xv[q][0]*xv[q][0] + xv[q][1]*xv[q][1]) + (xv[q][2]*xv[q][2] + xv[q][3]*xv[q][3]))
              + ((xv[q][4]*xv[q][4] + xv[q][5]*xv[q][5]) + (xv[q][6]*xv[q][6] + xv[q][7]*xv[q][7]));

    float bestE[4], bestO[4];
    int   idxE[4], idxO[4];
    #pragma unroll
    for (int q = 0; q < 4; ++q) {
        bestE[q] = 3.402823466e38f; bestO[q] = 3.402823466e38f;
        idxE[q] = 0; idxO[q] = 1;
    }

    // fused zero-stream: block's enc region = [ENC_OFF + blk*131072, +131072)
    // (%4==1): 3 head floats, 32767 aligned float4 slots, 1 tail float.
    float4* encb = (float4*)dout + (G4_BASE + (long long)blk * 32768);
    float*  encf = dout + (ENC_OFF + (long long)blk * 131072);
    const float4 z4 = make_float4(0.f, 0.f, 0.f, 0.f);
    const int phi = (blk * 149) & 255;              // per-block phase rotation

    // main loop: 256 k-pairs; iter i zeroes slot-pair ip = (i+phi) & 255
    // (2KB contiguous per wave per iter, write-once, content-independent).
    #pragma unroll 1
    for (int i = 0; i < 256; ++i) {
        const int k = i * 2;
        const float4* ek = (const float4*)(cb + (k << 3));  // rows k,k+1 (broadcast)
        float4 r0a = ek[0], r0b = ek[1], r1a = ek[2], r1b = ek[3];
        float2 s01 = *(const float2*)(sse + k);

        const int ip = (i + phi) & 255;
        encb[(size_t)(2 * ip) * 64 + L] = z4;
        if (ip != 255 || L != 63)                    // slot (511,63): boundary-spanning
            encb[(size_t)(2 * ip + 1) * 64 + L] = z4;

        #pragma unroll
        for (int q = 0; q < 4; ++q) {
            float d0 =       xv[q][0] * r0a.x;
            d0 = __builtin_fmaf(xv[q][1], r0a.y, d0);
            d0 = __builtin_fmaf(xv[q][2], r0a.z, d0);
            d0 = __builtin_fmaf(xv[q][3], r0a.w, d0);
            d0 = __builtin_fmaf(xv[q][4], r0b.x, d0);
            d0 = __builtin_fmaf(xv[q][5], r0b.y, d0);
            d0 = __builtin_fmaf(xv[q][6], r0b.z, d0);
            d0 = __builtin_fmaf(xv[q][7], r0b.w, d0);
            float dist0 = __builtin_fmaf(-2.0f, d0, sx[q] + s01.x);

            float d1 =       xv[q][0] * r1a.x;
            d1 = __builtin_fmaf(xv[q][1], r1a.y, d1);
            d1 = __builtin_fmaf(xv[q][2], r1a.z, d1);
            d1 = __builtin_fmaf(xv[q][3], r1a.w, d1);
            d1 = __builtin_fmaf(xv[q][4], r1b.x, d1);
            d1 = __builtin_fmaf(xv[q][5], r1b.y, d1);
            d1 = __builtin_fmaf(xv[q][6], r1b.z, d1);
            d1 = __builtin_fmaf(xv[q][7], r1b.w, d1);
            float dist1 = __builtin_fmaf(-2.0f, d1, sx[q] + s01.y);

            bool l0 = dist0 < bestE[q];
            bestE[q] = l0 ? dist0 : bestE[q];
            idxE[q]  = l0 ? k     : idxE[q];
            bool l1 = dist1 < bestO[q];
            bestO[q] = l1 ? dist1 : bestO[q];
            idxO[q]  = l1 ? k + 1 : idxO[q];
        }
    }

    // head / tail zeros of this block's region
    if (L < 3)   encf[L]      = 0.f;
    if (L == 63) encf[131071] = 0.f;

    // merge chains (global first-min tie rule)
    int bidx[4];
    #pragma unroll
    for (int q = 0; q < 4; ++q) {
        bool ow = (bestO[q] < bestE[q]) || ((bestO[q] == bestE[q]) && (idxO[q] < idxE[q]));
        bidx[q] = ow ? idxO[q] : idxE[q];
    }

    // all zero-stores of THIS wave complete, then scatter the ones
    asm volatile("s_waitcnt vmcnt(0)" ::: "memory");
    #pragma unroll
    for (int q = 0; q < 4; ++q)
        encf[(size_t)(q * 64 + L) * 512 + bidx[q]] = 1.0f;

    // out region + loss partial
    float part = 0.0f;
    float* outp = dout + OUT_OFF + (size_t)b * (8 * SPB) + s0 + L;
    #pragma unroll
    for (int q = 0; q < 4; ++q) {
        const float4* qr4 = (const float4*)(cb + (bidx[q] << 3));
        float4 qa = qr4[0], qb = qr4[1];
        float qv[8] = {qa.x, qa.y, qa.z, qa.w, qb.x, qb.y, qb.z, qb.w};
        #pragma unroll
        for (int c = 0; c < 8; ++c) {
            float dq = qv[c] - xv[q][c];
            part += dq * dq;
            outp[(size_t)c * SPB + q * 64] = qv[c];
        }
    }

    // deterministic wave tree reduction
    #pragma unroll
    for (int off = 32; off > 0; off >>= 1)
        part += __shfl_down(part, off, 64);
    if (L == 0) partials[blk] = part;
}

__global__ __launch_bounds__(256) void loss_kernel(const float* __restrict__ partials,
                                                   float* __restrict__ dout) {
    __shared__ float sred[256];
    int t = threadIdx.x;
    float a = 0.0f;
    for (int j = t; j < NBLK; j += 256) a += partials[j];  // fixed order
    sred[t] = a;
    __syncthreads();
    for (int off = 128; off > 0; off >>= 1) {
        if (t < off) sred[t] += sred[t + off];
        __syncthreads();
    }
    if (t == 0) {
        float m = sred[0] / 1769472.0f;
        m = fminf(fmaxf(m, 0.0f), 10.0f);
        dout[0] = m + 0.25f * m;   // q_latent + beta*e_latent (equal values)
    }
}

extern "C" void kernel_launch(void* const* d_in, const int* in_sizes, int n_in,
                              void* d_out, int out_size, void* d_ws, size_t ws_size,
                              hipStream_t stream) {
    const float* x = (const float*)d_in[0];
    const float* e = (const float*)d_in[1];
    float* dout     = (float*)d_out;
    float* partials = (float*)d_ws;     // 864 floats

    hipLaunchKernelGGL(vq_main,     dim3(NBLK), dim3(64),  0, stream, x, e, dout, partials);
    hipLaunchKernelGGL(loss_kernel, dim3(1),    dim3(256), 0, stream, partials, dout);
}